// Round 8
// baseline (243.087 us; speedup 1.0000x reference)
//
#include <hip/hip_runtime.h>

typedef __bf16 bf16_t;
typedef __bf16 bf16x8 __attribute__((ext_vector_type(8)));
typedef __bf16 bf16x4 __attribute__((ext_vector_type(4)));
typedef short short4v __attribute__((ext_vector_type(4)));
typedef float f32x4 __attribute__((ext_vector_type(4)));

#define D_MODEL 1024
#define NHEAD 16
#define HD 64
#define XLEN 1024
#define TLEN 4096
#define NBATCH 2
#define CEXP 0.18033688011112042f /* log2(e)/sqrt(64) */

typedef __attribute__((address_space(3))) bf16_t lds_bf16;
typedef const __attribute__((address_space(1))) bf16_t glb_bf16;

// ---------------- convert: fp32 -> bf16, 5 arrays in one launch ----------------
__global__ __launch_bounds__(256) void convert5(const float* __restrict__ prev, const float* __restrict__ ctx,
                                                const float* __restrict__ wq, const float* __restrict__ wk,
                                                const float* __restrict__ wv,
                                                bf16_t* __restrict__ prev_b, bf16_t* __restrict__ ctx_b,
                                                bf16_t* __restrict__ wq_b, bf16_t* __restrict__ wk_b,
                                                bf16_t* __restrict__ wv_b) {
    int b = blockIdx.x;
    const float* src; bf16_t* dst; int lb;
    if (b < 256)       { src = prev; dst = prev_b; lb = b; }
    else if (b < 1280) { src = ctx;  dst = ctx_b;  lb = b - 256; }
    else if (b < 1408) { src = wq;   dst = wq_b;   lb = b - 1280; }
    else if (b < 1536) { src = wk;   dst = wk_b;   lb = b - 1408; }
    else               { src = wv;   dst = wv_b;   lb = b - 1536; }
    const int base = lb * 8192 + threadIdx.x * 4;
#pragma unroll
    for (int i = 0; i < 8; ++i) {
        const int off = base + i * 1024;
        f32x4 f = *(const f32x4*)(src + off);
        bf16x4 h;
        h[0] = (bf16_t)f[0]; h[1] = (bf16_t)f[1]; h[2] = (bf16_t)f[2]; h[3] = (bf16_t)f[3];
        *(bf16x4*)(dst + off) = h;
    }
}

// ---------------- fused projection GEMM (Q epilogue now pre-scales by CEXP) ----------------
__global__ __launch_bounds__(256) void gemm_fused(const bf16_t* __restrict__ Xq, const bf16_t* __restrict__ Xc,
                                                  const bf16_t* __restrict__ wq, const bf16_t* __restrict__ wk,
                                                  const bf16_t* __restrict__ wv,
                                                  const float* __restrict__ bq, const float* __restrict__ bk,
                                                  const float* __restrict__ bv,
                                                  bf16_t* __restrict__ Qh, bf16_t* __restrict__ Kh,
                                                  bf16_t* __restrict__ Vt) {
    __shared__ bf16_t Ab[128][32];
    __shared__ bf16_t Bb[128][32];

    const int tid  = threadIdx.x;
    const int w    = tid >> 6;
    const int lane = tid & 63;
    const int q4   = lane >> 4;
    const int c    = lane & 15;

    const bf16_t* X; const bf16_t* W; const float* bias;
    int m0, n0, lshift, vmode;
    const int bid = blockIdx.x;
    if (bid < 128) {
        X = Xq; W = wq; bias = bq; lshift = 10; vmode = 0;
        m0 = (bid >> 3) * 128; n0 = (bid & 7) * 128;
    } else {
        const int b = bid - 128;
        const int xcd  = b & 7;
        const int s    = b >> 3;
        const int nb   = s >> 3;
        const int mgrp = s & 7;
        m0 = (mgrp * 8 + xcd) * 128;
        X = Xc; lshift = 12;
        if (nb < 8) { W = wk; bias = bk; vmode = 0; n0 = nb * 128; }
        else        { W = wv; bias = bv; vmode = 1; n0 = (nb - 8) * 128; }
    }
    const float osc = (bid < 128) ? CEXP : 1.0f;   // fold softmax scale into Q

    f32x4 acc[4][4];
#pragma unroll
    for (int i = 0; i < 4; ++i)
#pragma unroll
        for (int j = 0; j < 4; ++j) acc[i][j] = (f32x4){0.f, 0.f, 0.f, 0.f};

    const int mq = (w & 1) * 64;
    const int nq = (w >> 1) * 64;

    bf16_t* aBase = &Ab[0][0] + w * 512;
    bf16_t* bBase = &Bb[0][0] + w * 512;
    const bf16_t* gA = X + (size_t)(m0 + (tid >> 2)) * D_MODEL + (tid & 3) * 8;
    const bf16_t* gB = W + (size_t)(n0 + (tid >> 2)) * D_MODEL + (tid & 3) * 8;

    for (int kk = 0; kk < D_MODEL; kk += 32) {
        __syncthreads();
        __builtin_amdgcn_global_load_lds((glb_bf16*)(gA + kk), (lds_bf16*)aBase, 16, 0, 0);
        __builtin_amdgcn_global_load_lds((glb_bf16*)(gA + kk + (size_t)64 * D_MODEL), (lds_bf16*)(aBase + 2048), 16, 0, 0);
        __builtin_amdgcn_global_load_lds((glb_bf16*)(gB + kk), (lds_bf16*)bBase, 16, 0, 0);
        __builtin_amdgcn_global_load_lds((glb_bf16*)(gB + kk + (size_t)64 * D_MODEL), (lds_bf16*)(bBase + 2048), 16, 0, 0);
        __syncthreads();

        bf16x8 a[4], b[4];
#pragma unroll
        for (int i = 0; i < 4; ++i) a[i] = *(const bf16x8*)&Ab[mq + i * 16 + c][q4 * 8];
#pragma unroll
        for (int i = 0; i < 4; ++i) b[i] = *(const bf16x8*)&Bb[nq + i * 16 + c][q4 * 8];
#pragma unroll
        for (int mi = 0; mi < 4; ++mi)
#pragma unroll
            for (int ni = 0; ni < 4; ++ni)
                acc[mi][ni] = __builtin_amdgcn_mfma_f32_16x16x32_bf16(a[mi], b[ni], acc[mi][ni], 0, 0, 0);
    }

    float bv4[4];
#pragma unroll
    for (int ni = 0; ni < 4; ++ni) bv4[ni] = bias[n0 + nq + ni * 16 + c];

    const int headbase = (n0 + nq) >> 6;
    if (vmode == 0) {
        bf16_t* OutQK = (bid < 128) ? Qh : Kh;
        const int L = 1 << lshift;
#pragma unroll
        for (int mi = 0; mi < 4; ++mi) {
            const int mrow = m0 + mq + mi * 16 + q4 * 4;
            const int nb2  = mrow >> lshift;
            const int pos  = mrow & (L - 1);
            bf16_t* ob = OutQK + ((size_t)(nb2 * NHEAD + headbase) * L + pos) * HD;
#pragma unroll
            for (int ni = 0; ni < 4; ++ni) {
                const int d = ni * 16 + c;
#pragma unroll
                for (int r = 0; r < 4; ++r)
                    ob[(size_t)r * HD + d] = (bf16_t)((acc[mi][ni][r] + bv4[ni]) * osc);
            }
        }
    } else {
#pragma unroll
        for (int mi = 0; mi < 4; ++mi) {
            const int mrow = m0 + mq + mi * 16 + q4 * 4;
            const int nb2  = mrow >> 12;
            const int pos  = mrow & 4095;
            const int lin  = (pos & ~31) + ((pos >> 2) & 3) * 8 + ((pos >> 4) & 1) * 4;
#pragma unroll
            for (int ni = 0; ni < 4; ++ni) {
                const int d = ni * 16 + c;
                bf16x4 v4;
#pragma unroll
                for (int r = 0; r < 4; ++r) v4[r] = (bf16_t)(acc[mi][ni][r] + bv4[ni]);
                *(bf16x4*)(Vt + ((size_t)(nb2 * NHEAD + headbase) * HD + d) * TLEN + lin) = v4;
            }
        }
    }
}

// ---------------- flash attention v4: 16 q-rows/wave, 8 blocks/CU, LDS union ----------------
__global__ __launch_bounds__(256, 8) void attn_kernel(const bf16_t* __restrict__ Qh,
                                                      const bf16_t* __restrict__ Kh,
                                                      const bf16_t* __restrict__ Vt,
                                                      bf16_t* __restrict__ Opart,
                                                      float* __restrict__ Lpart) {
    __shared__ __align__(16) char smem[16384 + 256];
    bf16_t* Kt = (bf16_t*)smem;            // 4096 el (8 KB)
    bf16_t* Vs = Kt + 4096;                // 4096 el (8 KB)
    float*  Lb = (float*)(smem + 16384);   // 64 floats

    const int tid  = threadIdx.x;
    const int lane = tid & 63;
    const int w    = tid >> 6;
    const int q4   = lane >> 4;
    const int c    = lane & 15;

    const int bid = blockIdx.x;
    const int xcd = bid & 7;
    const int seq = bid >> 3;           // 0..255
    const int tq  = seq & 3;
    const int xb  = (seq >> 2) & 15;
    const int g   = seq >> 6;           // 0..3
    const int nh  = g * 8 + xcd;
    const int x0  = xb * 64 + w * 16;   // this wave's 16 q-rows

    const bf16_t* __restrict__ Kb = Kh + (size_t)nh * TLEN * HD;
    const bf16_t* __restrict__ Vb = Vt + (size_t)nh * HD * TLEN;

    // Q fragments (pre-scaled by CEXP in projection)
    bf16x8 qa[2];
    {
        const bf16_t* qr = Qh + ((size_t)nh * XLEN + x0 + c) * HD + q4 * 8;
        qa[0] = *(const bf16x8*)(qr);
        qa[1] = *(const bf16x8*)(qr + 32);
    }

    // staging geometry (XOR chunk swizzle, proven in R7)
    const int sRow0 = tid >> 3,   sRow1 = 32 + (tid >> 3);
    const int sCh   = tid & 7;
    const int kCol0 = ((sCh ^ (sRow0 & 7)) * 8);
    const int kCol1 = ((sCh ^ (sRow1 & 7)) * 8);
    bf16_t* ldsK0 = Kt + w * 512;
    bf16_t* ldsK1 = Kt + 2048 + w * 512;
    bf16_t* ldsV0 = Vs + w * 512;
    bf16_t* ldsV1 = Vs + 2048 + w * 512;

    // fragment read byte-offsets (chunk j in {q4, 4+q4}, row-XOR by c&7)
    const int ofs0 = c * 128 + ((q4 ^ (c & 7)) * 16);
    const int ofs1 = c * 128 + (((4 + q4) ^ (c & 7)) * 16);

    f32x4 o[4];
#pragma unroll
    for (int j = 0; j < 4; ++j) o[j] = (f32x4){0.f, 0.f, 0.f, 0.f};
    f32x4 lacc = (f32x4){0.f, 0.f, 0.f, 0.f};

#if __has_builtin(__builtin_amdgcn_mfma_f32_16x16x16bf16_1k)
    bf16x4 ones4; ones4[0] = (bf16_t)1.0f; ones4[1] = (bf16_t)1.0f; ones4[2] = (bf16_t)1.0f; ones4[3] = (bf16_t)1.0f;
    const short4v onesS = __builtin_bit_cast(short4v, ones4);
#else
    bf16x8 ones8;
#pragma unroll
    for (int j = 0; j < 8; ++j) ones8[j] = (bf16_t)1.0f;
#endif

    const int t0base = tq * (TLEN / 4);
    for (int s = 0; s < 16; ++s) {
        const int t0 = t0base + s * 64;
        __syncthreads();
        __builtin_amdgcn_global_load_lds((glb_bf16*)(Kb + (size_t)(t0 + sRow0) * HD + kCol0), (lds_bf16*)ldsK0, 16, 0, 0);
        __builtin_amdgcn_global_load_lds((glb_bf16*)(Kb + (size_t)(t0 + sRow1) * HD + kCol1), (lds_bf16*)ldsK1, 16, 0, 0);
        __builtin_amdgcn_global_load_lds((glb_bf16*)(Vb + (size_t)sRow0 * TLEN + t0 + kCol0), (lds_bf16*)ldsV0, 16, 0, 0);
        __builtin_amdgcn_global_load_lds((glb_bf16*)(Vb + (size_t)sRow1 * TLEN + t0 + kCol1), (lds_bf16*)ldsV1, 16, 0, 0);
        __syncthreads();

        const char* KtB = (const char*)Kt;
        const char* VsB = (const char*)Vs;
#pragma unroll
        for (int g32 = 0; g32 < 2; ++g32) {
            // S^T = K·Q^T (raw; scale pre-folded into Q), then p = exp2(s)
            bf16x4 pr[2];
#pragma unroll
            for (int tt = 0; tt < 2; ++tt) {
                const int rofs = g32 * 4096 + tt * 2048;
                bf16x8 kb0 = *(const bf16x8*)(KtB + rofs + ofs0);
                bf16x8 kb1 = *(const bf16x8*)(KtB + rofs + ofs1);
                f32x4 sv = (f32x4){0.f, 0.f, 0.f, 0.f};
                sv = __builtin_amdgcn_mfma_f32_16x16x32_bf16(kb0, qa[0], sv, 0, 0, 0);
                sv = __builtin_amdgcn_mfma_f32_16x16x32_bf16(kb1, qa[1], sv, 0, 0, 0);
                bf16x4 p4;
#pragma unroll
                for (int r = 0; r < 4; ++r) p4[r] = (bf16_t)__builtin_exp2f(sv[r]);
                pr[tt] = p4;
            }
            const int vsel = g32 ? ofs1 : ofs0;
#if __has_builtin(__builtin_amdgcn_mfma_f32_16x16x16bf16_1k)
#pragma unroll
            for (int tt = 0; tt < 2; ++tt) {
                const short4v pb = __builtin_bit_cast(short4v, pr[tt]);
#pragma unroll
                for (int dt = 0; dt < 4; ++dt) {
                    bf16x4 va = *(const bf16x4*)(VsB + vsel + dt * 2048 + tt * 8);
                    o[dt] = __builtin_amdgcn_mfma_f32_16x16x16bf16_1k(
                        __builtin_bit_cast(short4v, va), pb, o[dt], 0, 0, 0);
                }
                lacc = __builtin_amdgcn_mfma_f32_16x16x16bf16_1k(onesS, pb, lacc, 0, 0, 0);
            }
#else
#pragma unroll
            for (int tt = 0; tt < 2; ++tt) {
                bf16x8 p8;
#pragma unroll
                for (int j = 0; j < 4; ++j) { p8[j] = pr[tt][j]; p8[4 + j] = (bf16_t)0.0f; }
#pragma unroll
                for (int dt = 0; dt < 4; ++dt) {
                    bf16x4 va = *(const bf16x4*)(VsB + vsel + dt * 2048 + tt * 8);
                    bf16x8 va8;
#pragma unroll
                    for (int j = 0; j < 4; ++j) { va8[j] = va[j]; va8[4 + j] = (bf16_t)0.0f; }
                    o[dt] = __builtin_amdgcn_mfma_f32_16x16x32_bf16(va8, p8, o[dt], 0, 0, 0);
                }
                lacc = __builtin_amdgcn_mfma_f32_16x16x32_bf16(ones8, p8, lacc, 0, 0, 0);
            }
#endif
        }
    }

    // ---- epilogue: LDS union over Kt/Vs (all loop reads done after barrier) ----
    __syncthreads();
    bf16_t* ObW = ((bf16_t*)smem) + w * 1152;   // 16 rows x 72 per wave
    if (q4 == 0) Lb[w * 16 + c] = lacc[0];
#pragma unroll
    for (int dt = 0; dt < 4; ++dt)
#pragma unroll
        for (int r = 0; r < 4; ++r)
            ObW[c * 72 + dt * 16 + q4 * 4 + r] = (bf16_t)o[dt][r];
    // wave-internal DS ordering: no barrier needed for own slab
    {
        const int m  = lane >> 2;           // 0..15
        const int dq = (lane & 3) * 16;
        bf16x8 v0 = *(const bf16x8*)&ObW[m * 72 + dq];
        bf16x8 v1 = *(const bf16x8*)&ObW[m * 72 + dq + 8];
        const size_t pair = (size_t)nh * XLEN + x0 + m;
        bf16_t* op = Opart + (pair * 4 + tq) * HD + dq;
        *(bf16x8*)(op)     = v0;
        *(bf16x8*)(op + 8) = v1;
        if ((lane & 3) == 0) Lpart[pair * 4 + tq] = Lb[w * 16 + m];
    }
}

// ---------------- merge 4 T-quarter partials, normalize, write fp32 ----------------
__global__ __launch_bounds__(256) void attn_merge(const bf16_t* __restrict__ Opart,
                                                  const float* __restrict__ Lpart,
                                                  float* __restrict__ Out) {
    const int u    = blockIdx.x * 256 + threadIdx.x;
    const int pair = u >> 3;              // nh*1024 + x
    const int d0   = (u & 7) * 8;
    const int nh   = pair >> 10;
    const int x    = pair & 1023;
    const int n    = nh >> 4;
    const int h    = nh & 15;

    float l = 0.f;
    float s[8];
#pragma unroll
    for (int j = 0; j < 8; ++j) s[j] = 0.f;
#pragma unroll
    for (int tqi = 0; tqi < 4; ++tqi) {
        l += Lpart[pair * 4 + tqi];
        bf16x8 v = *(const bf16x8*)(Opart + ((size_t)pair * 4 + tqi) * HD + d0);
#pragma unroll
        for (int j = 0; j < 8; ++j) s[j] += (float)v[j];
    }
    const float inv = 1.0f / l;
    f32x4 v0, v1;
#pragma unroll
    for (int j = 0; j < 4; ++j) { v0[j] = s[j] * inv; v1[j] = s[4 + j] * inv; }
    float* op = Out + ((size_t)(n * XLEN + x)) * D_MODEL + h * HD + d0;
    *(f32x4*)(op)     = v0;
    *(f32x4*)(op + 4) = v1;
}

extern "C" void kernel_launch(void* const* d_in, const int* in_sizes, int n_in,
                              void* d_out, int out_size, void* d_ws, size_t ws_size,
                              hipStream_t stream) {
    (void)in_sizes; (void)n_in; (void)out_size; (void)ws_size;
    const float* prev = (const float*)d_in[0];
    const float* ctx  = (const float*)d_in[1];
    const float* Wq   = (const float*)d_in[2];
    const float* bq   = (const float*)d_in[3];
    const float* Wk   = (const float*)d_in[4];
    const float* bk   = (const float*)d_in[5];
    const float* Wv   = (const float*)d_in[6];
    const float* bv   = (const float*)d_in[7];

    const size_t MiB = 1024 * 1024;
    char* ws = (char*)d_ws;
    bf16_t* prev_b = (bf16_t*)(ws);                //  4 MiB -- dead after gemm -> Lpart
    bf16_t* ctx_b  = (bf16_t*)(ws + 4 * MiB);      // 16 MiB -- dead after gemm -> Opart
    bf16_t* wq_b   = (bf16_t*)(ws + 20 * MiB);     //  2 MiB
    bf16_t* wk_b   = (bf16_t*)(ws + 22 * MiB);     //  2 MiB
    bf16_t* wv_b   = (bf16_t*)(ws + 24 * MiB);     //  2 MiB
    bf16_t* Qh     = (bf16_t*)(ws + 26 * MiB);     //  4 MiB
    bf16_t* Kh     = (bf16_t*)(ws + 30 * MiB);     // 16 MiB
    bf16_t* Vt     = (bf16_t*)(ws + 46 * MiB);     // 16 MiB (total 62 MiB)
    bf16_t* Opart  = ctx_b;                        // 16 MiB overlay
    float*  Lpart  = (float*)prev_b;               // 512 KiB overlay

    convert5<<<1664, 256, 0, stream>>>(prev, ctx, Wq, Wk, Wv, prev_b, ctx_b, wq_b, wk_b, wv_b);
    gemm_fused<<<128 + 1024, 256, 0, stream>>>(prev_b, ctx_b, wq_b, wk_b, wv_b, bq, bk, bv, Qh, Kh, Vt);
    attn_kernel<<<2048, 256, 0, stream>>>(Qh, Kh, Vt, Opart, Lpart);
    attn_merge<<<1024, 256, 0, stream>>>(Opart, Lpart, (float*)d_out);
}

// Round 9
// 209.614 us; speedup vs baseline: 1.1597x; 1.1597x over previous
//
#include <hip/hip_runtime.h>

typedef __bf16 bf16_t;
typedef __bf16 bf16x8 __attribute__((ext_vector_type(8)));
typedef __bf16 bf16x4 __attribute__((ext_vector_type(4)));
typedef float f32x4 __attribute__((ext_vector_type(4)));

#define D_MODEL 1024
#define NHEAD 16
#define HD 64
#define XLEN 1024
#define TLEN 4096
#define NBATCH 2
#define CEXP 0.18033688011112042f /* log2(e)/sqrt(64) */

typedef __attribute__((address_space(3))) bf16_t lds_bf16;
typedef const __attribute__((address_space(1))) bf16_t glb_bf16;

// ---------------- convert: fp32 -> bf16, 5 arrays in one launch ----------------
__global__ __launch_bounds__(256) void convert5(const float* __restrict__ prev, const float* __restrict__ ctx,
                                                const float* __restrict__ wq, const float* __restrict__ wk,
                                                const float* __restrict__ wv,
                                                bf16_t* __restrict__ prev_b, bf16_t* __restrict__ ctx_b,
                                                bf16_t* __restrict__ wq_b, bf16_t* __restrict__ wk_b,
                                                bf16_t* __restrict__ wv_b) {
    int b = blockIdx.x;
    const float* src; bf16_t* dst; int lb;
    if (b < 256)       { src = prev; dst = prev_b; lb = b; }
    else if (b < 1280) { src = ctx;  dst = ctx_b;  lb = b - 256; }
    else if (b < 1408) { src = wq;   dst = wq_b;   lb = b - 1280; }
    else if (b < 1536) { src = wk;   dst = wk_b;   lb = b - 1408; }
    else               { src = wv;   dst = wv_b;   lb = b - 1536; }
    const int base = lb * 8192 + threadIdx.x * 4;
#pragma unroll
    for (int i = 0; i < 8; ++i) {
        const int off = base + i * 1024;
        f32x4 f = *(const f32x4*)(src + off);
        bf16x4 h;
        h[0] = (bf16_t)f[0]; h[1] = (bf16_t)f[1]; h[2] = (bf16_t)f[2]; h[3] = (bf16_t)f[3];
        *(bf16x4*)(dst + off) = h;
    }
}

// ---------------- fused projection GEMM (Q epilogue pre-scales by CEXP) ----------------
__global__ __launch_bounds__(256) void gemm_fused(const bf16_t* __restrict__ Xq, const bf16_t* __restrict__ Xc,
                                                  const bf16_t* __restrict__ wq, const bf16_t* __restrict__ wk,
                                                  const bf16_t* __restrict__ wv,
                                                  const float* __restrict__ bq, const float* __restrict__ bk,
                                                  const float* __restrict__ bv,
                                                  bf16_t* __restrict__ Qh, bf16_t* __restrict__ Kh,
                                                  bf16_t* __restrict__ Vt) {
    __shared__ bf16_t Ab[128][32];
    __shared__ bf16_t Bb[128][32];

    const int tid  = threadIdx.x;
    const int w    = tid >> 6;
    const int lane = tid & 63;
    const int q4   = lane >> 4;
    const int c    = lane & 15;

    const bf16_t* X; const bf16_t* W; const float* bias;
    int m0, n0, lshift, vmode;
    const int bid = blockIdx.x;
    if (bid < 128) {
        X = Xq; W = wq; bias = bq; lshift = 10; vmode = 0;
        m0 = (bid >> 3) * 128; n0 = (bid & 7) * 128;
    } else {
        const int b = bid - 128;
        const int xcd  = b & 7;
        const int s    = b >> 3;
        const int nb   = s >> 3;
        const int mgrp = s & 7;
        m0 = (mgrp * 8 + xcd) * 128;
        X = Xc; lshift = 12;
        if (nb < 8) { W = wk; bias = bk; vmode = 0; n0 = nb * 128; }
        else        { W = wv; bias = bv; vmode = 1; n0 = (nb - 8) * 128; }
    }
    const float osc = (bid < 128) ? CEXP : 1.0f;

    f32x4 acc[4][4];
#pragma unroll
    for (int i = 0; i < 4; ++i)
#pragma unroll
        for (int j = 0; j < 4; ++j) acc[i][j] = (f32x4){0.f, 0.f, 0.f, 0.f};

    const int mq = (w & 1) * 64;
    const int nq = (w >> 1) * 64;

    bf16_t* aBase = &Ab[0][0] + w * 512;
    bf16_t* bBase = &Bb[0][0] + w * 512;
    const bf16_t* gA = X + (size_t)(m0 + (tid >> 2)) * D_MODEL + (tid & 3) * 8;
    const bf16_t* gB = W + (size_t)(n0 + (tid >> 2)) * D_MODEL + (tid & 3) * 8;

    for (int kk = 0; kk < D_MODEL; kk += 32) {
        __syncthreads();
        __builtin_amdgcn_global_load_lds((glb_bf16*)(gA + kk), (lds_bf16*)aBase, 16, 0, 0);
        __builtin_amdgcn_global_load_lds((glb_bf16*)(gA + kk + (size_t)64 * D_MODEL), (lds_bf16*)(aBase + 2048), 16, 0, 0);
        __builtin_amdgcn_global_load_lds((glb_bf16*)(gB + kk), (lds_bf16*)bBase, 16, 0, 0);
        __builtin_amdgcn_global_load_lds((glb_bf16*)(gB + kk + (size_t)64 * D_MODEL), (lds_bf16*)(bBase + 2048), 16, 0, 0);
        __syncthreads();

        bf16x8 a[4], b[4];
#pragma unroll
        for (int i = 0; i < 4; ++i) a[i] = *(const bf16x8*)&Ab[mq + i * 16 + c][q4 * 8];
#pragma unroll
        for (int i = 0; i < 4; ++i) b[i] = *(const bf16x8*)&Bb[nq + i * 16 + c][q4 * 8];
#pragma unroll
        for (int mi = 0; mi < 4; ++mi)
#pragma unroll
            for (int ni = 0; ni < 4; ++ni)
                acc[mi][ni] = __builtin_amdgcn_mfma_f32_16x16x32_bf16(a[mi], b[ni], acc[mi][ni], 0, 0, 0);
    }

    float bv4[4];
#pragma unroll
    for (int ni = 0; ni < 4; ++ni) bv4[ni] = bias[n0 + nq + ni * 16 + c];

    const int headbase = (n0 + nq) >> 6;
    if (vmode == 0) {
        bf16_t* OutQK = (bid < 128) ? Qh : Kh;
        const int L = 1 << lshift;
#pragma unroll
        for (int mi = 0; mi < 4; ++mi) {
            const int mrow = m0 + mq + mi * 16 + q4 * 4;
            const int nb2  = mrow >> lshift;
            const int pos  = mrow & (L - 1);
            bf16_t* ob = OutQK + ((size_t)(nb2 * NHEAD + headbase) * L + pos) * HD;
#pragma unroll
            for (int ni = 0; ni < 4; ++ni) {
                const int d = ni * 16 + c;
#pragma unroll
                for (int r = 0; r < 4; ++r)
                    ob[(size_t)r * HD + d] = (bf16_t)((acc[mi][ni][r] + bv4[ni]) * osc);
            }
        }
    } else {
#pragma unroll
        for (int mi = 0; mi < 4; ++mi) {
            const int mrow = m0 + mq + mi * 16 + q4 * 4;
            const int nb2  = mrow >> 12;
            const int pos  = mrow & 4095;
            const int lin  = (pos & ~31) + ((pos >> 2) & 3) * 8 + ((pos >> 4) & 1) * 4;
#pragma unroll
            for (int ni = 0; ni < 4; ++ni) {
                const int d = ni * 16 + c;
                bf16x4 v4;
#pragma unroll
                for (int r = 0; r < 4; ++r) v4[r] = (bf16_t)(acc[mi][ni][r] + bv4[ni]);
                *(bf16x4*)(Vt + ((size_t)(nb2 * NHEAD + headbase) * HD + d) * TLEN + lin) = v4;
            }
        }
    }
}

// ---------------- flash attention v5: 32 q-rows/wave, PV K=32, double-buffered LDS ----------------
__global__ __launch_bounds__(256, 4) void attn_kernel(const bf16_t* __restrict__ Qh,
                                                      const bf16_t* __restrict__ Kh,
                                                      const bf16_t* __restrict__ Vt,
                                                      bf16_t* __restrict__ Opart,
                                                      float* __restrict__ Lpart) {
    __shared__ __align__(16) char smem[32768];   // 2 bufs x (Kt 8KB | Vs 8KB); epilogue overlays

    const int tid  = threadIdx.x;
    const int lane = tid & 63;
    const int w    = tid >> 6;
    const int q4   = lane >> 4;
    const int c    = lane & 15;

    const int bid = blockIdx.x;
    const int xcd = bid & 7;
    const int seq = bid >> 3;           // 0..127
    const int tq  = seq & 3;
    const int xb  = (seq >> 2) & 7;
    const int g   = seq >> 5;           // 0..3
    const int nh  = g * 8 + xcd;
    const int xw  = xb * 128 + w * 32;

    const bf16_t* __restrict__ Kb = Kh + (size_t)nh * TLEN * HD;
    const bf16_t* __restrict__ Vb = Vt + (size_t)nh * HD * TLEN;

    // Q fragments (pre-scaled by CEXP in projection)
    bf16x8 qa[2][2];
#pragma unroll
    for (int mi = 0; mi < 2; ++mi) {
        const bf16_t* qr = Qh + ((size_t)nh * XLEN + xw + mi * 16 + c) * HD + q4 * 8;
        qa[mi][0] = *(const bf16x8*)(qr);
        qa[mi][1] = *(const bf16x8*)(qr + 32);
    }

    // staging geometry (XOR chunk swizzle)
    const int sRow0 = tid >> 3,  sRow1 = 32 + (tid >> 3);
    const int sCh   = tid & 7;
    const int kCol0 = ((sCh ^ (sRow0 & 7)) * 8);
    const int kCol1 = ((sCh ^ (sRow1 & 7)) * 8);

    // fragment read byte-offsets
    const int ofs0 = c * 128 + ((q4 ^ (c & 7)) * 16);
    const int ofs1 = c * 128 + (((4 + q4) ^ (c & 7)) * 16);

    f32x4 o[2][4];
#pragma unroll
    for (int i = 0; i < 2; ++i)
#pragma unroll
        for (int j = 0; j < 4; ++j) o[i][j] = (f32x4){0.f, 0.f, 0.f, 0.f};
    f32x4 lacc[2];
    lacc[0] = (f32x4){0.f, 0.f, 0.f, 0.f};
    lacc[1] = (f32x4){0.f, 0.f, 0.f, 0.f};

    bf16x8 ones8;
#pragma unroll
    for (int j = 0; j < 8; ++j) ones8[j] = (bf16_t)1.0f;

    const int t0base = tq * (TLEN / 4);

    // prologue: issue loads for stage 0 into buf 0
    {
        bf16_t* base = (bf16_t*)smem;
        __builtin_amdgcn_global_load_lds((glb_bf16*)(Kb + (size_t)(t0base + sRow0) * HD + kCol0), (lds_bf16*)(base + w * 512), 16, 0, 0);
        __builtin_amdgcn_global_load_lds((glb_bf16*)(Kb + (size_t)(t0base + sRow1) * HD + kCol1), (lds_bf16*)(base + 2048 + w * 512), 16, 0, 0);
        __builtin_amdgcn_global_load_lds((glb_bf16*)(Vb + (size_t)sRow0 * TLEN + t0base + kCol0), (lds_bf16*)(base + 4096 + w * 512), 16, 0, 0);
        __builtin_amdgcn_global_load_lds((glb_bf16*)(Vb + (size_t)sRow1 * TLEN + t0base + kCol1), (lds_bf16*)(base + 6144 + w * 512), 16, 0, 0);
    }

    for (int s = 0; s < 16; ++s) {
        __syncthreads();   // drains vmcnt -> stage s ready; prev compute reads done
        if (s < 15) {      // prefetch s+1 into the other buffer (lands during compute)
            const int t1 = t0base + (s + 1) * 64;
            bf16_t* base = (bf16_t*)smem + ((s + 1) & 1) * 8192;
            __builtin_amdgcn_global_load_lds((glb_bf16*)(Kb + (size_t)(t1 + sRow0) * HD + kCol0), (lds_bf16*)(base + w * 512), 16, 0, 0);
            __builtin_amdgcn_global_load_lds((glb_bf16*)(Kb + (size_t)(t1 + sRow1) * HD + kCol1), (lds_bf16*)(base + 2048 + w * 512), 16, 0, 0);
            __builtin_amdgcn_global_load_lds((glb_bf16*)(Vb + (size_t)sRow0 * TLEN + t1 + kCol0), (lds_bf16*)(base + 4096 + w * 512), 16, 0, 0);
            __builtin_amdgcn_global_load_lds((glb_bf16*)(Vb + (size_t)sRow1 * TLEN + t1 + kCol1), (lds_bf16*)(base + 6144 + w * 512), 16, 0, 0);
        }

        const char* KtB = smem + (s & 1) * 16384;
        const char* VsB = KtB + 8192;
#pragma unroll
        for (int g32 = 0; g32 < 2; ++g32) {
            // S^T = K·Q^T -> p8 per mi (k = q4*8 + tt*4 + r, matching V's t-perm)
            bf16x8 p8[2];
#pragma unroll
            for (int tt = 0; tt < 2; ++tt) {
                const int rofs = g32 * 4096 + tt * 2048;
                bf16x8 kb0 = *(const bf16x8*)(KtB + rofs + ofs0);
                bf16x8 kb1 = *(const bf16x8*)(KtB + rofs + ofs1);
#pragma unroll
                for (int mi = 0; mi < 2; ++mi) {
                    f32x4 sv = (f32x4){0.f, 0.f, 0.f, 0.f};
                    sv = __builtin_amdgcn_mfma_f32_16x16x32_bf16(kb0, qa[mi][0], sv, 0, 0, 0);
                    sv = __builtin_amdgcn_mfma_f32_16x16x32_bf16(kb1, qa[mi][1], sv, 0, 0, 0);
#pragma unroll
                    for (int r = 0; r < 4; ++r)
                        p8[mi][tt * 4 + r] = (bf16_t)__builtin_exp2f(sv[r]);
                }
            }
            // O += P V at K=32 (V A-fragment is one contiguous b128)
            const int vsel = g32 ? ofs1 : ofs0;
            bf16x8 va[4];
#pragma unroll
            for (int dt = 0; dt < 4; ++dt)
                va[dt] = *(const bf16x8*)(VsB + vsel + dt * 2048);
#pragma unroll
            for (int mi = 0; mi < 2; ++mi) {
#pragma unroll
                for (int dt = 0; dt < 4; ++dt)
                    o[mi][dt] = __builtin_amdgcn_mfma_f32_16x16x32_bf16(va[dt], p8[mi], o[mi][dt], 0, 0, 0);
                lacc[mi] = __builtin_amdgcn_mfma_f32_16x16x32_bf16(ones8, p8[mi], lacc[mi], 0, 0, 0);
            }
        }
    }

    // ---- epilogue: overlay LDS, transpose, write partials ----
    __syncthreads();
    bf16_t* Ob = (bf16_t*)smem;                 // [w][64 d][33 m]
    float*  Lb = (float*)(smem + 16896);        // [w][32]
#pragma unroll
    for (int mi = 0; mi < 2; ++mi) {
        if (q4 == 0) Lb[w * 32 + mi * 16 + c] = lacc[mi][0];
#pragma unroll
        for (int dt = 0; dt < 4; ++dt)
#pragma unroll
            for (int r = 0; r < 4; ++r)
                Ob[w * 2112 + (dt * 16 + q4 * 4 + r) * 33 + mi * 16 + c] = (bf16_t)o[mi][dt][r];
    }
    // wave-internal DS ordering: no barrier needed for own slab
    {
        const int lr = lane >> 1;               // row 0..31
        const int dh = lane & 1;                // d half
        bf16x8 out4[4];
#pragma unroll
        for (int j2 = 0; j2 < 4; ++j2)
#pragma unroll
            for (int e = 0; e < 8; ++e)
                out4[j2][e] = Ob[w * 2112 + (dh * 32 + j2 * 8 + e) * 33 + lr];
        const size_t pair = (size_t)nh * XLEN + xw + lr;
        bf16_t* op = Opart + (pair * 4 + tq) * HD + dh * 32;
#pragma unroll
        for (int j2 = 0; j2 < 4; ++j2)
            *(bf16x8*)(op + j2 * 8) = out4[j2];
        if (dh == 0) Lpart[pair * 4 + tq] = Lb[w * 32 + lr];
    }
}

// ---------------- merge 4 T-quarter partials, normalize, write fp32 ----------------
__global__ __launch_bounds__(256) void attn_merge(const bf16_t* __restrict__ Opart,
                                                  const float* __restrict__ Lpart,
                                                  float* __restrict__ Out) {
    const int u    = blockIdx.x * 256 + threadIdx.x;
    const int pair = u >> 3;              // nh*1024 + x
    const int d0   = (u & 7) * 8;
    const int nh   = pair >> 10;
    const int x    = pair & 1023;
    const int n    = nh >> 4;
    const int h    = nh & 15;

    float l = 0.f;
    float s[8];
#pragma unroll
    for (int j = 0; j < 8; ++j) s[j] = 0.f;
#pragma unroll
    for (int tqi = 0; tqi < 4; ++tqi) {
        l += Lpart[pair * 4 + tqi];
        bf16x8 v = *(const bf16x8*)(Opart + ((size_t)pair * 4 + tqi) * HD + d0);
#pragma unroll
        for (int j = 0; j < 8; ++j) s[j] += (float)v[j];
    }
    const float inv = 1.0f / l;
    f32x4 v0, v1;
#pragma unroll
    for (int j = 0; j < 4; ++j) { v0[j] = s[j] * inv; v1[j] = s[4 + j] * inv; }
    float* op = Out + ((size_t)(n * XLEN + x)) * D_MODEL + h * HD + d0;
    *(f32x4*)(op)     = v0;
    *(f32x4*)(op + 4) = v1;
}

extern "C" void kernel_launch(void* const* d_in, const int* in_sizes, int n_in,
                              void* d_out, int out_size, void* d_ws, size_t ws_size,
                              hipStream_t stream) {
    (void)in_sizes; (void)n_in; (void)out_size; (void)ws_size;
    const float* prev = (const float*)d_in[0];
    const float* ctx  = (const float*)d_in[1];
    const float* Wq   = (const float*)d_in[2];
    const float* bq   = (const float*)d_in[3];
    const float* Wk   = (const float*)d_in[4];
    const float* bk   = (const float*)d_in[5];
    const float* Wv   = (const float*)d_in[6];
    const float* bv   = (const float*)d_in[7];

    const size_t MiB = 1024 * 1024;
    char* ws = (char*)d_ws;
    bf16_t* prev_b = (bf16_t*)(ws);                //  4 MiB -- dead after gemm -> Lpart
    bf16_t* ctx_b  = (bf16_t*)(ws + 4 * MiB);      // 16 MiB -- dead after gemm -> Opart
    bf16_t* wq_b   = (bf16_t*)(ws + 20 * MiB);     //  2 MiB
    bf16_t* wk_b   = (bf16_t*)(ws + 22 * MiB);     //  2 MiB
    bf16_t* wv_b   = (bf16_t*)(ws + 24 * MiB);     //  2 MiB
    bf16_t* Qh     = (bf16_t*)(ws + 26 * MiB);     //  4 MiB
    bf16_t* Kh     = (bf16_t*)(ws + 30 * MiB);     // 16 MiB
    bf16_t* Vt     = (bf16_t*)(ws + 46 * MiB);     // 16 MiB (total 62 MiB)
    bf16_t* Opart  = ctx_b;                        // 16 MiB overlay
    float*  Lpart  = (float*)prev_b;               // 512 KiB overlay

    convert5<<<1664, 256, 0, stream>>>(prev, ctx, Wq, Wk, Wv, prev_b, ctx_b, wq_b, wk_b, wv_b);
    gemm_fused<<<128 + 1024, 256, 0, stream>>>(prev_b, ctx_b, wq_b, wk_b, wv_b, bq, bk, bv, Qh, Kh, Vt);
    attn_kernel<<<1024, 256, 0, stream>>>(Qh, Kh, Vt, Opart, Lpart);
    attn_merge<<<1024, 256, 0, stream>>>(Opart, Lpart, (float*)d_out);
}